// Round 1
// baseline (1465.998 us; speedup 1.0000x reference)
//
#include <hip/hip_runtime.h>

#define H 128

// ---------------- CSR build ----------------

__global__ void hist_kernel(const int* __restrict__ ids, int* __restrict__ cnt, int n) {
  int i = blockIdx.x * blockDim.x + threadIdx.x;
  if (i < n) atomicAdd(&cnt[ids[i]], 1);
}

__global__ void fill_adj_kernel(const int* __restrict__ src, const int* __restrict__ dst,
                                int* __restrict__ cursor, int* __restrict__ adj, int n) {
  int i = blockIdx.x * blockDim.x + threadIdx.x;
  if (i < n) {
    int p = atomicAdd(&cursor[dst[i]], 1);
    adj[p] = src[i];
  }
}

// single-block exclusive scan (wave-shuffle based, ~3 barriers per 1024 elems)
__global__ __launch_bounds__(1024) void scan_kernel(const int* __restrict__ in,
                                                    int* __restrict__ out,
                                                    int* __restrict__ out2, int n) {
  __shared__ int wsum[16];
  __shared__ int carry_s;
  int t = threadIdx.x;
  int lane = t & 63, w = t >> 6;
  if (t == 0) carry_s = 0;
  __syncthreads();
  for (int base = 0; base < n; base += 1024) {
    int i = base + t;
    int v = (i < n) ? in[i] : 0;
    int acc = v;
    #pragma unroll
    for (int off = 1; off < 64; off <<= 1) {
      int g = __shfl_up(acc, off, 64);
      if (lane >= off) acc += g;
    }
    if (lane == 63) wsum[w] = acc;
    __syncthreads();
    int woff = 0;
    for (int j = 0; j < w; ++j) woff += wsum[j];
    int excl = carry_s + woff + acc - v;
    if (i < n) { out[i] = excl; if (out2) out2[i] = excl; }
    __syncthreads();
    if (t == 1023) carry_s += woff + acc;
    __syncthreads();
  }
  if (t == 0) { out[n] = carry_s; if (out2) out2[n] = carry_s; }
}

// ---------------- GIN aggregate: z[v] = (1+eps)*h[v] + sum_{u in N_in(v)} h[u] ----------------

__global__ __launch_bounds__(256) void aggregate_kernel(
    const float* __restrict__ h, float* __restrict__ z,
    const int* __restrict__ row_ptr, const int* __restrict__ adj,
    const float* __restrict__ eps, int layer, int n)
{
  int wid = (blockIdx.x * 256 + threadIdx.x) >> 6;   // one wave per node
  int lane = threadIdx.x & 63;
  if (wid >= n) return;
  float e = 1.0f + eps[layer];
  int beg = row_ptr[wid], end = row_ptr[wid + 1];
  const float2* hv = (const float2*)h;
  float2 a = hv[(size_t)wid * 64 + lane];
  float sx = a.x * e, sy = a.y * e;
  int p = beg;
  int u_next = (p < end) ? adj[p] : 0;
  while (p < end) {
    int u = u_next;
    ++p;
    if (p < end) u_next = adj[p];          // prefetch next neighbor id
    float2 b = hv[(size_t)u * 64 + lane];  // coalesced 512B row read
    sx += b.x; sy += b.y;
  }
  float2 o; o.x = sx; o.y = sy;
  ((float2*)z)[(size_t)wid * 64 + lane] = o;
}

// ---------------- fused GEMM: out = maybe_relu( (A@W + bias) bn ) ----------------
// out[r][c] = epi( sum_k A[r][k]*W[k][c] ), epi(v) = relu?( v*S[c] + T[c] )
// S = g*rsqrt(var+eps), T = (bias - m)*S + beta   (null ptrs -> identity)
// In-place (out==A) is safe: block owns its 64 rows; __syncthreads before stores.

__global__ __launch_bounds__(256, 2) void gemm128_kernel(
    const float* __restrict__ A, const float* __restrict__ W, float* __restrict__ out,
    const float* __restrict__ bias, const float* __restrict__ gw,
    const float* __restrict__ bb, const float* __restrict__ bm,
    const float* __restrict__ bv, int relu, int nrows)
{
  __shared__ float Ws[H * H];   // 64 KB
  int t = threadIdx.x;
  {
    const float4* Wv = (const float4*)W;
    float4* Sv = (float4*)Ws;
    #pragma unroll
    for (int i = 0; i < 16; ++i) Sv[t + i * 256] = Wv[t + i * 256];
  }
  __syncthreads();

  int cg = t & 15;          // 16 col groups: cols cg*4..cg*4+3 and +64
  int rp = t >> 4;          // 16 row groups of 4 rows
  int row0 = blockIdx.x * 64 + rp * 4;

  const float* Ar[4];
  #pragma unroll
  for (int r = 0; r < 4; ++r) {
    int rr = row0 + r; if (rr > nrows - 1) rr = nrows - 1;   // clamp (last block only)
    Ar[r] = A + (size_t)rr * H;
  }

  float acc[4][8];
  #pragma unroll
  for (int r = 0; r < 4; ++r)
    #pragma unroll
    for (int j = 0; j < 8; ++j) acc[r][j] = 0.0f;

  float a[4][4], an[4][4];
  #pragma unroll
  for (int r = 0; r < 4; ++r) *(float4*)&a[r][0] = *(const float4*)(Ar[r]);

  for (int k4 = 0; k4 < H; k4 += 4) {
    int kn = k4 + 4;
    if (kn < H) {
      #pragma unroll
      for (int r = 0; r < 4; ++r) *(float4*)&an[r][0] = *(const float4*)(Ar[r] + kn);
    }
    #pragma unroll
    for (int kk = 0; kk < 4; ++kk) {
      float4 w0 = *(const float4*)&Ws[(k4 + kk) * H + cg * 4];
      float4 w1 = *(const float4*)&Ws[(k4 + kk) * H + cg * 4 + 64];
      #pragma unroll
      for (int r = 0; r < 4; ++r) {
        float av = a[r][kk];
        acc[r][0] += av * w0.x; acc[r][1] += av * w0.y;
        acc[r][2] += av * w0.z; acc[r][3] += av * w0.w;
        acc[r][4] += av * w1.x; acc[r][5] += av * w1.y;
        acc[r][6] += av * w1.z; acc[r][7] += av * w1.w;
      }
    }
    #pragma unroll
    for (int r = 0; r < 4; ++r)
      #pragma unroll
      for (int j = 0; j < 4; ++j) a[r][j] = an[r][j];
  }
  __syncthreads();   // all A reads done -> in-place store safe

  float S[8], T[8];
  #pragma unroll
  for (int j = 0; j < 8; ++j) {
    int c = cg * 4 + (j & 3) + ((j >> 2) << 6);
    float sc = bv ? rsqrtf(bv[c] + 1e-5f) : 1.0f;
    float gg = gw ? gw[c] : 1.0f;
    float Sj = gg * sc;
    float Tj = ((bias ? bias[c] : 0.0f) - (bm ? bm[c] : 0.0f)) * Sj + (bb ? bb[c] : 0.0f);
    S[j] = Sj; T[j] = Tj;
  }
  #pragma unroll
  for (int r = 0; r < 4; ++r) {
    int row = row0 + r;
    if (row < nrows) {
      float o[8];
      #pragma unroll
      for (int j = 0; j < 8; ++j) {
        float vv = acc[r][j] * S[j] + T[j];
        if (relu) vv = fmaxf(vv, 0.0f);
        o[j] = vv;
      }
      *(float4*)(out + (size_t)row * H + cg * 4) = *(float4*)&o[0];
      *(float4*)(out + (size_t)row * H + cg * 4 + 64) = *(float4*)&o[4];
    }
  }
}

// ---------------- mean pool over sorted batch segments ----------------

__global__ void pool_kernel(const float* __restrict__ h, float* __restrict__ pooled,
                            const int* __restrict__ gptr) {
  int g = blockIdx.x, c = threadIdx.x;   // 128 threads = 128 cols
  int beg = gptr[g], end = gptr[g + 1];
  float s = 0.0f;
  for (int i = beg; i < end; ++i) s += h[(size_t)i * H + c];
  float cnt = (float)(end - beg);
  pooled[(size_t)g * H + c] = s / fmaxf(cnt, 1.0f);
}

// ---------------- launch ----------------

extern "C" void kernel_launch(void* const* d_in, const int* in_sizes, int n_in,
                              void* d_out, int out_size, void* d_ws, size_t ws_size,
                              hipStream_t stream) {
  const float* x      = (const float*)d_in[0];
  const int*   ei     = (const int*)d_in[1];
  const int*   batch  = (const int*)d_in[2];
  const float* enc_W  = (const float*)d_in[3];
  const float* enc_b  = (const float*)d_in[4];
  const float* eps    = (const float*)d_in[5];
  const float* mlp1_W = (const float*)d_in[6];
  const float* mlp1_b = (const float*)d_in[7];
  const float* mlp1_g = (const float*)d_in[8];
  const float* mlp1_be= (const float*)d_in[9];
  const float* mlp1_m = (const float*)d_in[10];
  const float* mlp1_v = (const float*)d_in[11];
  const float* mlp2_W = (const float*)d_in[12];
  const float* mlp2_b = (const float*)d_in[13];
  const float* bn_g   = (const float*)d_in[14];
  const float* bn_b   = (const float*)d_in[15];
  const float* bn_m   = (const float*)d_in[16];
  const float* bn_v   = (const float*)d_in[17];
  const float* hW1    = (const float*)d_in[18];
  const float* hb1    = (const float*)d_in[19];
  const float* hg     = (const float*)d_in[20];
  const float* hbe    = (const float*)d_in[21];
  const float* hm     = (const float*)d_in[22];
  const float* hv     = (const float*)d_in[23];
  const float* hW2    = (const float*)d_in[24];
  const float* hb2    = (const float*)d_in[25];

  const int N = in_sizes[0] / H;   // 100000
  const int E = in_sizes[1] / 2;   // 1600000
  const int G = out_size / H;      // 512
  const int L = in_sizes[5];       // 3

  const int* src = ei;
  const int* dst = ei + E;

  char* p = (char*)d_ws;
  auto alloc = [&](size_t bytes) -> char* {
    char* r = p;
    p += (bytes + 255) & ~(size_t)255;
    return r;
  };
  float* bufA   = (float*)alloc((size_t)N * H * sizeof(float));
  float* bufB   = (float*)alloc((size_t)N * H * sizeof(float));
  int*   adj    = (int*)alloc((size_t)E * sizeof(int));
  int*   deg    = (int*)alloc((size_t)N * sizeof(int));
  int*   row_ptr= (int*)alloc((size_t)(N + 1) * sizeof(int));
  int*   cursor = (int*)alloc((size_t)(N + 1) * sizeof(int));
  int*   gcount = (int*)alloc((size_t)G * sizeof(int));
  int*   gptr   = (int*)alloc((size_t)(G + 1) * sizeof(int));
  float* pooled = (float*)alloc((size_t)G * H * sizeof(float));
  float* z1     = (float*)alloc((size_t)G * H * sizeof(float));

  hipMemsetAsync(deg, 0, (size_t)N * sizeof(int), stream);
  hipMemsetAsync(gcount, 0, (size_t)G * sizeof(int), stream);

  hist_kernel<<<(E + 255) / 256, 256, 0, stream>>>(dst, deg, E);
  hist_kernel<<<(N + 255) / 256, 256, 0, stream>>>(batch, gcount, N);
  scan_kernel<<<1, 1024, 0, stream>>>(deg, row_ptr, cursor, N);
  scan_kernel<<<1, 1024, 0, stream>>>(gcount, gptr, nullptr, G);
  fill_adj_kernel<<<(E + 255) / 256, 256, 0, stream>>>(src, dst, cursor, adj, E);

  // node encoder: h = x @ enc_W + enc_b
  gemm128_kernel<<<(N + 63) / 64, 256, 0, stream>>>(
      x, enc_W, bufA, enc_b, nullptr, nullptr, nullptr, nullptr, 0, N);

  float* cur = bufA;
  float* nxt = bufB;
  for (int l = 0; l < L; ++l) {
    aggregate_kernel<<<(N + 3) / 4, 256, 0, stream>>>(cur, nxt, row_ptr, adj, eps, l, N);
    gemm128_kernel<<<(N + 63) / 64, 256, 0, stream>>>(
        nxt, mlp1_W + (size_t)l * H * H, nxt,
        mlp1_b + l * H, mlp1_g + l * H, mlp1_be + l * H, mlp1_m + l * H, mlp1_v + l * H, 1, N);
    gemm128_kernel<<<(N + 63) / 64, 256, 0, stream>>>(
        nxt, mlp2_W + (size_t)l * H * H, nxt,
        mlp2_b + l * H, bn_g + l * H, bn_b + l * H, bn_m + l * H, bn_v + l * H, 1, N);
    float* tmp = cur; cur = nxt; nxt = tmp;
  }

  pool_kernel<<<G, 128, 0, stream>>>(cur, pooled, gptr);

  gemm128_kernel<<<(G + 63) / 64, 256, 0, stream>>>(
      pooled, hW1, z1, hb1, hg, hbe, hm, hv, 1, G);
  gemm128_kernel<<<(G + 63) / 64, 256, 0, stream>>>(
      z1, hW2, (float*)d_out, hb2, nullptr, nullptr, nullptr, nullptr, 0, G);
}

// Round 2
// 1024.397 us; speedup vs baseline: 1.4311x; 1.4311x over previous
//
#include <hip/hip_runtime.h>

#define H 128

typedef __attribute__((ext_vector_type(8))) short short8v;   // 8 bf16 (4 VGPRs)
typedef __attribute__((ext_vector_type(4))) float f32x4;

// ---------------- bf16 split helpers ----------------

__device__ inline unsigned short bfr(float x) {
  unsigned u = __float_as_uint(x);
  return (unsigned short)((u + 0x8000u) >> 16);   // round-half-up to bf16
}
__device__ inline float ubf(unsigned short h) {
  return __uint_as_float(((unsigned)h) << 16);
}
__device__ inline void bsplit(float x, unsigned short& h, unsigned short& l) {
  h = bfr(x);
  l = bfr(x - ubf(h));   // residual exactly representable (Sterbenz)
}

// ---------------- CSR build ----------------

__global__ void hist_kernel(const int* __restrict__ ids, int* __restrict__ cnt, int n) {
  int i = blockIdx.x * blockDim.x + threadIdx.x;
  if (i < n) atomicAdd(&cnt[ids[i]], 1);
}

__global__ void fill_adj_kernel(const int* __restrict__ src, const int* __restrict__ dst,
                                int* __restrict__ cursor, int* __restrict__ adj, int n) {
  int i = blockIdx.x * blockDim.x + threadIdx.x;
  if (i < n) {
    int p = atomicAdd(&cursor[dst[i]], 1);
    adj[p] = src[i];
  }
}

// ---- hierarchical scan: scan1 (per-block excl) -> scan2 (block sums) -> scan3 (add) ----

__global__ __launch_bounds__(1024) void scan1_kernel(const int* __restrict__ in,
                                                     int* __restrict__ out,
                                                     int* __restrict__ bsum, int n) {
  __shared__ int wsum[16];
  int t = threadIdx.x;
  int i = blockIdx.x * 1024 + t;
  int lane = t & 63, w = t >> 6;
  int v = (i < n) ? in[i] : 0;
  int acc = v;
  #pragma unroll
  for (int off = 1; off < 64; off <<= 1) {
    int g = __shfl_up(acc, off, 64);
    if (lane >= off) acc += g;
  }
  if (lane == 63) wsum[w] = acc;
  __syncthreads();
  int woff = 0;
  for (int j = 0; j < w; ++j) woff += wsum[j];
  if (i < n) out[i] = woff + acc - v;
  if (t == 1023) bsum[blockIdx.x] = woff + acc;
}

__global__ __launch_bounds__(256) void scan2_kernel(int* __restrict__ bsum, int nb) {
  __shared__ int s[256];
  int t = threadIdx.x;
  s[t] = (t < nb) ? bsum[t] : 0;
  __syncthreads();
  #pragma unroll
  for (int off = 1; off < 256; off <<= 1) {
    int v = (t >= off) ? s[t - off] : 0;
    __syncthreads();
    s[t] += v;
    __syncthreads();
  }
  if (t < nb) bsum[t] = (t == 0) ? 0 : s[t - 1];
}

__global__ __launch_bounds__(1024) void scan3_kernel(const int* __restrict__ bsum,
                                                     const int* __restrict__ deg,
                                                     int* __restrict__ rp,
                                                     int* __restrict__ cur, int n) {
  int i = blockIdx.x * 1024 + threadIdx.x;
  if (i < n) {
    int v = rp[i] + bsum[blockIdx.x];
    rp[i] = v;
    cur[i] = v;
    if (i == n - 1) rp[n] = v + deg[i];
  }
}

// small single-block scan (for gptr, n<=1024): writes out[0..n] (out[n]=total)
__global__ __launch_bounds__(1024) void scan_small_kernel(const int* __restrict__ in,
                                                          int* __restrict__ out, int n) {
  __shared__ int wsum[16];
  int t = threadIdx.x;
  int lane = t & 63, w = t >> 6;
  int v = (t < n) ? in[t] : 0;
  int acc = v;
  #pragma unroll
  for (int off = 1; off < 64; off <<= 1) {
    int g = __shfl_up(acc, off, 64);
    if (lane >= off) acc += g;
  }
  if (lane == 63) wsum[w] = acc;
  __syncthreads();
  int woff = 0;
  for (int j = 0; j < w; ++j) woff += wsum[j];
  if (t < n) out[t] = woff + acc - v;
  if (t == n - 1) out[n] = woff + acc;
}

// ---------------- GIN aggregate: z[v] = (1+eps)*h[v] + sum_{u in N_in(v)} h[u] ----------------

__global__ __launch_bounds__(256) void aggregate_kernel(
    const float* __restrict__ h, float* __restrict__ z,
    const int* __restrict__ row_ptr, const int* __restrict__ adj,
    const float* __restrict__ eps, int layer, int n)
{
  int wid = (blockIdx.x * 256 + threadIdx.x) >> 6;   // one wave per node
  int lane = threadIdx.x & 63;
  if (wid >= n) return;
  float e = 1.0f + eps[layer];
  int beg = row_ptr[wid], end = row_ptr[wid + 1];
  const float2* hv = (const float2*)h;
  float2 a = hv[(size_t)wid * 64 + lane];
  float sx = a.x * e, sy = a.y * e;
  int p = beg;
  // 4 independent row loads in flight per iteration (memory-level parallelism)
  for (; p + 4 <= end; p += 4) {
    int u0 = adj[p], u1 = adj[p + 1], u2 = adj[p + 2], u3 = adj[p + 3];
    float2 b0 = hv[(size_t)u0 * 64 + lane];
    float2 b1 = hv[(size_t)u1 * 64 + lane];
    float2 b2 = hv[(size_t)u2 * 64 + lane];
    float2 b3 = hv[(size_t)u3 * 64 + lane];
    sx += (b0.x + b1.x) + (b2.x + b3.x);
    sy += (b0.y + b1.y) + (b2.y + b3.y);
  }
  for (; p < end; ++p) {
    int u = adj[p];
    float2 b = hv[(size_t)u * 64 + lane];
    sx += b.x; sy += b.y;
  }
  float2 o; o.x = sx; o.y = sy;
  ((float2*)z)[(size_t)wid * 64 + lane] = o;
}

// ---------------- W prep: fp32 [k][c] -> split-bf16, transposed, swizzled planes ----------------
// Per matrix m: hi plane Wt[m*32768 .. +16384), lo plane next 16384 (ushort elements).
// Granule (col, kg): 8 contiguous k (k = kg*8..kg*8+7) of column col, stored at
// granule index g2 = col*16 + (kg ^ (col & 7))  (16B XOR swizzle baked into global layout).

__global__ __launch_bounds__(256) void prep_w_kernel(
    const float* w0, const float* w1, const float* w2, const float* w3, const float* w4,
    const float* w5, const float* w6, const float* w7, const float* w8,
    unsigned short* __restrict__ Wt)
{
  int m = blockIdx.x >> 3;                 // 9 matrices x 8 blocks
  int bb = blockIdx.x & 7;
  const float* ws[9] = {w0, w1, w2, w3, w4, w5, w6, w7, w8};
  const float* W = ws[m];
  unsigned short* hi = Wt + (size_t)m * 32768;
  unsigned short* lo = hi + 16384;
  int gid = bb * 256 + threadIdx.x;        // 0..2047
  int col = gid & 127;
  int kg  = gid >> 7;                      // 0..15
  short8v vh, vl;
  #pragma unroll
  for (int j = 0; j < 8; ++j) {
    float v = W[(kg * 8 + j) * H + col];   // coalesced across lanes (col consecutive)
    unsigned short h, l;
    bsplit(v, h, l);
    vh[j] = (short)h;
    vl[j] = (short)l;
  }
  int g2 = col * 16 + (kg ^ (col & 7));
  *(short8v*)(hi + (size_t)g2 * 8) = vh;
  *(short8v*)(lo + (size_t)g2 * 8) = vl;
}

// ---------------- MFMA GEMM: out = maybe_relu((A@W + bias) bn) ----------------
// A fp32 [nrows][128] row-major, W pre-split planes (see prep_w_kernel).
// 4-term split-bf16: AhWh + AlWh + AhWl + AlWl, fp32 MFMA accumulate.
// Block = 256 thr (4 waves), 128 rows x 128 cols. Wave: 32 rows (2 frags) x 128 cols (8 frags).
// In-place safe: each wave reads only its own rows, stores after its k-loop.

__global__ __launch_bounds__(256, 2) void gemm_mfma_kernel(
    const float* __restrict__ A, const unsigned short* __restrict__ Wt,
    float* __restrict__ out,
    const float* __restrict__ bias, const float* __restrict__ gw,
    const float* __restrict__ bb_, const float* __restrict__ bm,
    const float* __restrict__ bv, int relu, int nrows)
{
  __shared__ float4 ldsv[4096];            // 64 KB: hi plane 16384 ushort, lo plane 16384 ushort
  unsigned short* lds = (unsigned short*)ldsv;
  int t = threadIdx.x;

  { // linear 64KB stage (swizzle pre-baked in global layout)
    const float4* srcv = (const float4*)Wt;
    #pragma unroll
    for (int i = 0; i < 16; ++i) ldsv[t + 256 * i] = srcv[t + 256 * i];
  }
  __syncthreads();

  int w = t >> 6, l = t & 63;
  int lr = l & 15;          // fragment row/col index
  int lk = l >> 4;          // k sub-block (0..3)
  int row0 = blockIdx.x * 128 + w * 32;

  f32x4 acc[2][8];
  #pragma unroll
  for (int m = 0; m < 2; ++m)
    #pragma unroll
    for (int n = 0; n < 8; ++n) acc[m][n] = (f32x4){0.f, 0.f, 0.f, 0.f};

  const float* Ap[2];
  #pragma unroll
  for (int m = 0; m < 2; ++m) {
    int r = row0 + m * 16 + lr;
    if (r > nrows - 1) r = nrows - 1;      // clamp (tail block only)
    Ap[m] = A + (size_t)r * H + lk * 8;
  }

  #pragma unroll
  for (int k4 = 0; k4 < 4; ++k4) {
    short8v ah[2], al[2];
    #pragma unroll
    for (int m = 0; m < 2; ++m) {
      f32x4 a0 = *(const f32x4*)(Ap[m] + k4 * 32);
      f32x4 a1 = *(const f32x4*)(Ap[m] + k4 * 32 + 4);
      #pragma unroll
      for (int j = 0; j < 4; ++j) {
        unsigned short hh, ll;
        bsplit(a0[j], hh, ll); ah[m][j] = (short)hh; al[m][j] = (short)ll;
        bsplit(a1[j], hh, ll); ah[m][4 + j] = (short)hh; al[m][4 + j] = (short)ll;
      }
    }
    int kg = k4 * 4 + lk;
    #pragma unroll
    for (int n = 0; n < 8; ++n) {
      int col = n * 16 + lr;
      int g2 = col * 16 + (kg ^ (col & 7));
      short8v wh = *(const short8v*)(lds + (size_t)g2 * 8);
      short8v wl = *(const short8v*)(lds + 16384 + (size_t)g2 * 8);
      acc[0][n] = __builtin_amdgcn_mfma_f32_16x16x32_bf16(ah[0], wh, acc[0][n], 0, 0, 0);
      acc[1][n] = __builtin_amdgcn_mfma_f32_16x16x32_bf16(ah[1], wh, acc[1][n], 0, 0, 0);
      acc[0][n] = __builtin_amdgcn_mfma_f32_16x16x32_bf16(al[0], wh, acc[0][n], 0, 0, 0);
      acc[1][n] = __builtin_amdgcn_mfma_f32_16x16x32_bf16(al[1], wh, acc[1][n], 0, 0, 0);
      acc[0][n] = __builtin_amdgcn_mfma_f32_16x16x32_bf16(ah[0], wl, acc[0][n], 0, 0, 0);
      acc[1][n] = __builtin_amdgcn_mfma_f32_16x16x32_bf16(ah[1], wl, acc[1][n], 0, 0, 0);
      acc[0][n] = __builtin_amdgcn_mfma_f32_16x16x32_bf16(al[0], wl, acc[0][n], 0, 0, 0);
      acc[1][n] = __builtin_amdgcn_mfma_f32_16x16x32_bf16(al[1], wl, acc[1][n], 0, 0, 0);
    }
  }

  // epilogue: v*S[c] + T[c], optional relu.  C/D layout: col = lane&15, row = lk*4 + reg.
  #pragma unroll
  for (int n = 0; n < 8; ++n) {
    int c = n * 16 + lr;
    float sc = bv ? rsqrtf(bv[c] + 1e-5f) : 1.0f;
    float gg = gw ? gw[c] : 1.0f;
    float S = gg * sc;
    float T = ((bias ? bias[c] : 0.0f) - (bm ? bm[c] : 0.0f)) * S + (bb_ ? bb_[c] : 0.0f);
    #pragma unroll
    for (int m = 0; m < 2; ++m) {
      int rowb = row0 + m * 16 + lk * 4;
      #pragma unroll
      for (int r = 0; r < 4; ++r) {
        int row = rowb + r;
        if (row < nrows) {
          float vv = acc[m][n][r] * S + T;
          if (relu) vv = fmaxf(vv, 0.0f);
          out[(size_t)row * H + c] = vv;
        }
      }
    }
  }
}

// ---------------- mean pool over sorted batch segments ----------------

__global__ __launch_bounds__(128) void pool_kernel(const float* __restrict__ h,
                                                   float* __restrict__ pooled,
                                                   const int* __restrict__ gptr) {
  int g = blockIdx.x, c = threadIdx.x;   // 128 threads = 128 cols
  int beg = gptr[g], end = gptr[g + 1];
  float s = 0.0f;
  int i = beg;
  for (; i + 4 <= end; i += 4) {
    float a0 = h[(size_t)i * H + c];
    float a1 = h[(size_t)(i + 1) * H + c];
    float a2 = h[(size_t)(i + 2) * H + c];
    float a3 = h[(size_t)(i + 3) * H + c];
    s += (a0 + a1) + (a2 + a3);
  }
  for (; i < end; ++i) s += h[(size_t)i * H + c];
  float cnt = (float)(end - beg);
  pooled[(size_t)g * H + c] = s / fmaxf(cnt, 1.0f);
}

// ---------------- launch ----------------

extern "C" void kernel_launch(void* const* d_in, const int* in_sizes, int n_in,
                              void* d_out, int out_size, void* d_ws, size_t ws_size,
                              hipStream_t stream) {
  const float* x      = (const float*)d_in[0];
  const int*   ei     = (const int*)d_in[1];
  const int*   batch  = (const int*)d_in[2];
  const float* enc_W  = (const float*)d_in[3];
  const float* enc_b  = (const float*)d_in[4];
  const float* eps    = (const float*)d_in[5];
  const float* mlp1_W = (const float*)d_in[6];
  const float* mlp1_b = (const float*)d_in[7];
  const float* mlp1_g = (const float*)d_in[8];
  const float* mlp1_be= (const float*)d_in[9];
  const float* mlp1_m = (const float*)d_in[10];
  const float* mlp1_v = (const float*)d_in[11];
  const float* mlp2_W = (const float*)d_in[12];
  const float* mlp2_b = (const float*)d_in[13];
  const float* bn_g   = (const float*)d_in[14];
  const float* bn_b   = (const float*)d_in[15];
  const float* bn_m   = (const float*)d_in[16];
  const float* bn_v   = (const float*)d_in[17];
  const float* hW1    = (const float*)d_in[18];
  const float* hb1    = (const float*)d_in[19];
  const float* hg     = (const float*)d_in[20];
  const float* hbe    = (const float*)d_in[21];
  const float* hm     = (const float*)d_in[22];
  const float* hv     = (const float*)d_in[23];
  const float* hW2    = (const float*)d_in[24];
  const float* hb2    = (const float*)d_in[25];

  const int N = in_sizes[0] / H;   // 100000
  const int E = in_sizes[1] / 2;   // 1600000
  const int G = out_size / H;      // 512
  const int L = in_sizes[5];       // 3

  const int* src = ei;
  const int* dst = ei + E;

  char* p = (char*)d_ws;
  auto alloc = [&](size_t bytes) -> char* {
    char* r = p;
    p += (bytes + 255) & ~(size_t)255;
    return r;
  };
  float* bufA   = (float*)alloc((size_t)N * H * sizeof(float));
  float* bufB   = (float*)alloc((size_t)N * H * sizeof(float));
  int*   adj    = (int*)alloc((size_t)E * sizeof(int));
  int*   deg    = (int*)alloc((size_t)N * sizeof(int));
  int*   row_ptr= (int*)alloc((size_t)(N + 1) * sizeof(int));
  int*   cursor = (int*)alloc((size_t)(N + 1) * sizeof(int));
  int*   bsum   = (int*)alloc(256 * sizeof(int));
  int*   gcount = (int*)alloc((size_t)G * sizeof(int));
  int*   gptr   = (int*)alloc((size_t)(G + 1) * sizeof(int));
  float* pooled = (float*)alloc((size_t)G * H * sizeof(float));
  float* z1     = (float*)alloc((size_t)G * H * sizeof(float));
  unsigned short* Wt = (unsigned short*)alloc((size_t)9 * 32768 * sizeof(unsigned short));

  hipMemsetAsync(deg, 0, (size_t)N * sizeof(int), stream);
  hipMemsetAsync(gcount, 0, (size_t)G * sizeof(int), stream);

  hist_kernel<<<(E + 255) / 256, 256, 0, stream>>>(dst, deg, E);
  hist_kernel<<<(N + 255) / 256, 256, 0, stream>>>(batch, gcount, N);

  int nb = (N + 1023) / 1024;
  scan1_kernel<<<nb, 1024, 0, stream>>>(deg, row_ptr, bsum, N);
  scan2_kernel<<<1, 256, 0, stream>>>(bsum, nb);
  scan3_kernel<<<nb, 1024, 0, stream>>>(bsum, deg, row_ptr, cursor, N);
  scan_small_kernel<<<1, 1024, 0, stream>>>(gcount, gptr, G);

  fill_adj_kernel<<<(E + 255) / 256, 256, 0, stream>>>(src, dst, cursor, adj, E);

  // pre-split/transpose/swizzle all 9 weight matrices
  prep_w_kernel<<<9 * 8, 256, 0, stream>>>(
      enc_W,
      mlp1_W, mlp1_W + (size_t)H * H, mlp1_W + (size_t)2 * H * H,
      mlp2_W, mlp2_W + (size_t)H * H, mlp2_W + (size_t)2 * H * H,
      hW1, hW2, Wt);

  // node encoder: h = x @ enc_W + enc_b
  gemm_mfma_kernel<<<(N + 127) / 128, 256, 0, stream>>>(
      x, Wt + 0 * 32768, bufA, enc_b, nullptr, nullptr, nullptr, nullptr, 0, N);

  float* cur = bufA;
  float* nxt = bufB;
  for (int l = 0; l < L; ++l) {
    aggregate_kernel<<<(N + 3) / 4, 256, 0, stream>>>(cur, nxt, row_ptr, adj, eps, l, N);
    gemm_mfma_kernel<<<(N + 127) / 128, 256, 0, stream>>>(
        nxt, Wt + (size_t)(1 + l) * 32768, nxt,
        mlp1_b + l * H, mlp1_g + l * H, mlp1_be + l * H, mlp1_m + l * H, mlp1_v + l * H, 1, N);
    gemm_mfma_kernel<<<(N + 127) / 128, 256, 0, stream>>>(
        nxt, Wt + (size_t)(4 + l) * 32768, nxt,
        mlp2_b + l * H, bn_g + l * H, bn_b + l * H, bn_m + l * H, bn_v + l * H, 1, N);
    float* tmp = cur; cur = nxt; nxt = tmp;
  }

  pool_kernel<<<G, 128, 0, stream>>>(cur, pooled, gptr);

  gemm_mfma_kernel<<<(G + 127) / 128, 256, 0, stream>>>(
      pooled, Wt + (size_t)7 * 32768, z1, hb1, hg, hbe, hm, hv, 1, G);
  gemm_mfma_kernel<<<(G + 127) / 128, 256, 0, stream>>>(
      z1, Wt + (size_t)8 * 32768, (float*)d_out, hb2, nullptr, nullptr, nullptr, nullptr, 0, G);
}